// Round 3
// baseline (204.146 us; speedup 1.0000x reference)
//
#include <hip/hip_runtime.h>

#define B_ 4
#define QN 512
#define KVN 512
#define QD_ 512
#define H_ 256
#define VD_ 256

__device__ __forceinline__ float rcp_(float x) { return __builtin_amdgcn_rcpf(x); }
__device__ __forceinline__ float ex2_(float x) { return __builtin_amdgcn_exp2f(x); }

// ---------------- K1: fused projection GEMM, LDS-free (z=0: q·Wq, z=1: k·Wk) ------------
// C[r][h] = (sum_d A[r][d] * W[h][d]) * 2*log2(e).  A rows & W rows are k-major -> float4
// loads along k; A-row addrs broadcast across 8 lanes, W cached in L1/L2 (512 KB).
__global__ __launch_bounds__(128) void proj_fused(const float* __restrict__ q,
                                                  const float* __restrict__ k,
                                                  const float* __restrict__ Wq,
                                                  const float* __restrict__ Wk,
                                                  float* __restrict__ qh,
                                                  float* __restrict__ kh) {
    const float* A = blockIdx.z ? k : q;
    const float* W = blockIdx.z ? Wk : Wq;
    float* C = blockIdx.z ? kh : qh;
    int tid = threadIdx.x;
    int w2 = tid >> 6, lane = tid & 63;
    int tm = lane >> 3, tn = lane & 7;
    int r0 = blockIdx.y * 64 + w2 * 32 + tm;  // rows r0 + 8*i, i<4
    int h0 = blockIdx.x * 16 + tn;            // cols h0 + 8*j, j<2
    const float* a0 = A + (size_t)r0 * QD_;
    const float* w0 = W + (size_t)h0 * QD_;
    float c[4][2] = {};
    for (int kk = 0; kk < QD_; kk += 4) {
        float4 av[4], wr[2];
#pragma unroll
        for (int i = 0; i < 4; ++i) av[i] = *(const float4*)(a0 + (size_t)(8 * i) * QD_ + kk);
#pragma unroll
        for (int j = 0; j < 2; ++j) wr[j] = *(const float4*)(w0 + (size_t)(8 * j) * QD_ + kk);
#pragma unroll
        for (int i = 0; i < 4; ++i)
#pragma unroll
            for (int j = 0; j < 2; ++j) {
                c[i][j] = __builtin_fmaf(av[i].x, wr[j].x, c[i][j]);
                c[i][j] = __builtin_fmaf(av[i].y, wr[j].y, c[i][j]);
                c[i][j] = __builtin_fmaf(av[i].z, wr[j].z, c[i][j]);
                c[i][j] = __builtin_fmaf(av[i].w, wr[j].w, c[i][j]);
            }
    }
    const float cs = 2.8853900817779268f;  // 2*log2(e), prescale for scores' exp2
#pragma unroll
    for (int i = 0; i < 4; ++i)
#pragma unroll
        for (int j = 0; j < 2; ++j)
            C[(size_t)(r0 + 8 * i) * H_ + h0 + 8 * j] = c[i][j] * cs;
}

// ---------------- K2: LDS-free scores with 4-way rcp combine ----------------------------
// sc = -2 * sum_h wv[h]/(exp2(qh'+kh')+1)   (== scores - row-const; softmax-invariant)
// w0/a+w1/b+w2/c+w3/d = ((w0*b+w1*a)*cd + (w2*d+w3*c)*ab) * rcp(ab*cd): 5 trans / 4 evals
__global__ __launch_bounds__(256) void scores_kernel(const float* __restrict__ qh,
                                                     const float* __restrict__ kh,
                                                     const float* __restrict__ wv,
                                                     float* __restrict__ sc) {
    int b = blockIdx.z;
    int tid = threadIdx.x;
    int wvd = tid >> 6, lane = tid & 63;
    int tr = lane >> 4, tc = lane & 15;
    int row = blockIdx.y * 64 + wvd * 16 + tr * 4;  // rows row..row+3
    int col = blockIdx.x * 16 + tc;
    const float* qp = qh + ((size_t)(b * QN) + row) * H_;
    const float* kp = kh + ((size_t)(b * KVN) + col) * H_;
    float acc[4] = {};
    for (int h = 0; h < H_; h += 4) {
        float4 w4 = *(const float4*)(wv + h);  // uniform -> s_load
        float4 kv = *(const float4*)(kp + h);
        float4 qv[4];
#pragma unroll
        for (int i = 0; i < 4; ++i) qv[i] = *(const float4*)(qp + (size_t)i * H_ + h);
#pragma unroll
        for (int i = 0; i < 4; ++i) {
            float e0 = ex2_(qv[i].x + kv.x);
            float e1 = ex2_(qv[i].y + kv.y);
            float e2 = ex2_(qv[i].z + kv.z);
            float e3 = ex2_(qv[i].w + kv.w);
            float a = e0 + 1.0f, bb = e1 + 1.0f, cc = e2 + 1.0f, dd = e3 + 1.0f;
            float ab = a * bb, cd = cc * dd;
            float n1 = __builtin_fmaf(w4.y, a, w4.x * bb);
            float n2 = __builtin_fmaf(w4.w, cc, w4.z * dd);
            float num = __builtin_fmaf(n2, ab, n1 * cd);
            acc[i] = __builtin_fmaf(num, rcp_(ab * cd), acc[i]);
        }
    }
#pragma unroll
    for (int i = 0; i < 4; ++i)
        sc[((size_t)(b * QN) + row + i) * KVN + col] = -2.0f * acc[i];
}

// ---------------- K3: in-place softmax over last dim (512) ----------------
__global__ __launch_bounds__(256) void softmax_kernel(float* __restrict__ attn) {
    int row = blockIdx.x;
    int tid = threadIdx.x;
    float* p = attn + (size_t)row * KVN;
    float x0 = p[tid], x1 = p[tid + 256];
    float m = fmaxf(x0, x1);
#pragma unroll
    for (int d = 1; d < 64; d <<= 1) m = fmaxf(m, __shfl_xor(m, d));
    __shared__ float redm[4], reds[4];
    int wave = tid >> 6, lane = tid & 63;
    if (lane == 0) redm[wave] = m;
    __syncthreads();
    m = fmaxf(fmaxf(redm[0], redm[1]), fmaxf(redm[2], redm[3]));
    float e0 = __expf(x0 - m), e1 = __expf(x1 - m);
    float s = e0 + e1;
#pragma unroll
    for (int d = 1; d < 64; d <<= 1) s += __shfl_xor(s, d);
    if (lane == 0) reds[wave] = s;
    __syncthreads();
    s = reds[0] + reds[1] + reds[2] + reds[3];
    float inv = rcp_(s);
    p[tid] = e0 * inv;
    p[tid + 256] = e1 * inv;
}

// ---------------- K4: LDS-free NN GEMM  out[b][i][n] = sum_j attn[b][i][j]*v[b][j][n] ---
// attn rows read float4 along j (broadcast x8 lanes); v rows read float4 along n
// (coalesced 128B across 8 lanes); v is 512 KB/batch -> L2-resident.
__global__ __launch_bounds__(128) void out_gemm(const float* __restrict__ attn,
                                                const float* __restrict__ v,
                                                float* __restrict__ out) {
    int b = blockIdx.z;
    int tid = threadIdx.x;
    int w2 = tid >> 6, lane = tid & 63;
    int tm = lane >> 3, tn = lane & 7;
    int row = blockIdx.y * 64 + w2 * 32 + tm;  // rows row + 8*i
    int n4 = blockIdx.x * 32 + tn * 4;
    const float* ap = attn + ((size_t)(b * QN) + row) * KVN;
    const float* vp = v + (size_t)b * KVN * VD_;
    float4 c4[4] = {{0, 0, 0, 0}, {0, 0, 0, 0}, {0, 0, 0, 0}, {0, 0, 0, 0}};
    for (int kk = 0; kk < KVN; kk += 4) {
        float4 a[4], vr[4];
#pragma unroll
        for (int i = 0; i < 4; ++i) a[i] = *(const float4*)(ap + (size_t)(8 * i) * KVN + kk);
#pragma unroll
        for (int t = 0; t < 4; ++t) vr[t] = *(const float4*)(vp + (size_t)(kk + t) * VD_ + n4);
#pragma unroll
        for (int i = 0; i < 4; ++i) {
            c4[i].x = __builtin_fmaf(a[i].x, vr[0].x, c4[i].x);
            c4[i].y = __builtin_fmaf(a[i].x, vr[0].y, c4[i].y);
            c4[i].z = __builtin_fmaf(a[i].x, vr[0].z, c4[i].z);
            c4[i].w = __builtin_fmaf(a[i].x, vr[0].w, c4[i].w);
            c4[i].x = __builtin_fmaf(a[i].y, vr[1].x, c4[i].x);
            c4[i].y = __builtin_fmaf(a[i].y, vr[1].y, c4[i].y);
            c4[i].z = __builtin_fmaf(a[i].y, vr[1].z, c4[i].z);
            c4[i].w = __builtin_fmaf(a[i].y, vr[1].w, c4[i].w);
            c4[i].x = __builtin_fmaf(a[i].z, vr[2].x, c4[i].x);
            c4[i].y = __builtin_fmaf(a[i].z, vr[2].y, c4[i].y);
            c4[i].z = __builtin_fmaf(a[i].z, vr[2].z, c4[i].z);
            c4[i].w = __builtin_fmaf(a[i].z, vr[2].w, c4[i].w);
            c4[i].x = __builtin_fmaf(a[i].w, vr[3].x, c4[i].x);
            c4[i].y = __builtin_fmaf(a[i].w, vr[3].y, c4[i].y);
            c4[i].z = __builtin_fmaf(a[i].w, vr[3].z, c4[i].z);
            c4[i].w = __builtin_fmaf(a[i].w, vr[3].w, c4[i].w);
        }
    }
#pragma unroll
    for (int i = 0; i < 4; ++i)
        *(float4*)(out + ((size_t)(b * QN) + row + 8 * i) * VD_ + n4) = c4[i];
}

extern "C" void kernel_launch(void* const* d_in, const int* in_sizes, int n_in,
                              void* d_out, int out_size, void* d_ws, size_t ws_size,
                              hipStream_t stream) {
    const float* q  = (const float*)d_in[0];
    const float* k  = (const float*)d_in[1];
    const float* v  = (const float*)d_in[2];
    const float* Wq = (const float*)d_in[3];
    const float* Wk = (const float*)d_in[4];
    const float* wv = (const float*)d_in[5];
    float* out  = (float*)d_out;                   // [B, QN, VD]
    float* attn = out + (size_t)B_ * QN * VD_;     // [B, QN, KVN]
    float* qh = (float*)d_ws;                      // [B*QN, H] (prescaled by 2*log2e)
    float* kh = qh + (size_t)B_ * QN * H_;         // [B*KVN, H] (prescaled)

    proj_fused<<<dim3(H_ / 16, (B_ * QN) / 64, 2), 128, 0, stream>>>(q, k, Wq, Wk, qh, kh);
    scores_kernel<<<dim3(KVN / 16, QN / 64, B_), 256, 0, stream>>>(qh, kh, wv, attn);
    softmax_kernel<<<B_ * QN, 256, 0, stream>>>(attn);
    out_gemm<<<dim3(VD_ / 32, QN / 64, B_), 128, 0, stream>>>(attn, v, out);
}

// Round 4
// 159.909 us; speedup vs baseline: 1.2766x; 1.2766x over previous
//
#include <hip/hip_runtime.h>

#define B_ 4
#define QN 512
#define KVN 512
#define QD_ 512
#define H_ 256
#define VD_ 256

__device__ __forceinline__ float rcp_(float x) { return __builtin_amdgcn_rcpf(x); }
__device__ __forceinline__ float ex2_(float x) { return __builtin_amdgcn_exp2f(x); }

// ---------------- K1: C[r][h] = (sum_d A[r][d]*W[h][d]) * 2log2e ------------------------
// 256 thr / 4 waves; tile 64 rows x 32 cols (8 cols/wave); lanes = rows.
// A staged in LDS k-major float4 [kq][row] (consecutive-lane b128 reads, conflict-free);
// W read at wave-uniform addresses -> s_load, SGPR operand in v_fma.
__global__ __launch_bounds__(256) void proj_fused(const float* __restrict__ q,
                                                  const float* __restrict__ k,
                                                  const float* __restrict__ Wq,
                                                  const float* __restrict__ Wk,
                                                  float* __restrict__ qh,
                                                  float* __restrict__ kh) {
    const int z = blockIdx.z;
    const float* __restrict__ A = z ? k : q;
    const float* __restrict__ W = z ? Wk : Wq;
    float* __restrict__ C = z ? kh : qh;
    __shared__ float As[8 * 66 * 4];  // float4-tile [kq=8][row=64], rows padded ->66
    const int tid = threadIdx.x;
    const int lane = tid & 63;
    const int wid = __builtin_amdgcn_readfirstlane(tid >> 6);
    const int r0 = blockIdx.y * 64;
    const int h0 = blockIdx.x * 32 + wid * 8;
    const float* __restrict__ wp = W + (size_t)h0 * QD_;
    float acc[8] = {};
    for (int k0 = 0; k0 < QD_; k0 += 32) {
        __syncthreads();
#pragma unroll
        for (int rep = 0; rep < 2; ++rep) {
            int idx = tid + rep * 256;
            int row = idx >> 3, c4 = idx & 7;  // 8 lanes/row -> 128B contiguous global
            float4 v4 = *(const float4*)(A + (size_t)(r0 + row) * QD_ + k0 + c4 * 4);
            *(float4*)(As + (c4 * 66 + row) * 4) = v4;
        }
        __syncthreads();
#pragma unroll
        for (int kq = 0; kq < 8; ++kq) {
            float4 a = *(const float4*)(As + (kq * 66 + lane) * 4);
#pragma unroll
            for (int c = 0; c < 8; ++c) {
                float4 w4 = *(const float4*)(wp + (size_t)c * QD_ + k0 + kq * 4);
                acc[c] = __builtin_fmaf(a.x, w4.x, acc[c]);
                acc[c] = __builtin_fmaf(a.y, w4.y, acc[c]);
                acc[c] = __builtin_fmaf(a.z, w4.z, acc[c]);
                acc[c] = __builtin_fmaf(a.w, w4.w, acc[c]);
            }
        }
    }
    const float cs = 2.8853900817779268f;  // 2*log2(e): prescale for scores' exp2
    float* cp = C + (size_t)(r0 + lane) * H_ + h0;
    float4 o0 = {acc[0] * cs, acc[1] * cs, acc[2] * cs, acc[3] * cs};
    float4 o1 = {acc[4] * cs, acc[5] * cs, acc[6] * cs, acc[7] * cs};
    *(float4*)cp = o0;
    *(float4*)(cp + 4) = o1;
}

// ---------------- K2: sc = -2 * sum_h wv[h] * rcp(exp2(qh'+kh')+1) ----------------------
// (scores minus row-const sum(wv); softmax-invariant). 4-way rcp combine: 1.25 trans/eval.
// 128 thr / 2 waves; tile 32q x 32k; thread = 2q x 4k; LDS reads are b128 along h.
__global__ __launch_bounds__(128) void scores_kernel(const float* __restrict__ qh,
                                                     const float* __restrict__ kh,
                                                     const float* __restrict__ wv,
                                                     float* __restrict__ sc) {
    __shared__ float qs[32][68];
    __shared__ float ks[32][68];
    const int b = blockIdx.z;
    const int i0 = blockIdx.y * 32, j0 = blockIdx.x * 32;
    const int tid = threadIdx.x;
    const int w = tid >> 6, lane = tid & 63;
    const int ti = lane >> 3, tj = lane & 7;
    const int qr = 16 * w + ti;  // thread q-rows: qr, qr+8 ; k-cols: tj + 8*{0..3}
    float acc[2][4] = {};
    for (int h0 = 0; h0 < H_; h0 += 64) {
        __syncthreads();
#pragma unroll
        for (int t = 0; t < 8; ++t) {  // 1024 float4 units: t<4 -> qs, t>=4 -> ks
            int idx = tid + t * 128;
            int row = (idx >> 4) & 31, c = idx & 15;
            if (t < 4) {
                float4 v4 = *(const float4*)(qh + ((size_t)(b * QN + i0 + row)) * H_ + h0 + c * 4);
                *(float4*)&qs[row][c * 4] = v4;
            } else {
                float4 v4 = *(const float4*)(kh + ((size_t)(b * KVN + j0 + row)) * H_ + h0 + c * 4);
                *(float4*)&ks[row][c * 4] = v4;
            }
        }
        __syncthreads();
#pragma unroll 4
        for (int hh = 0; hh < 64; hh += 4) {
            float4 w4 = *(const float4*)(wv + h0 + hh);  // wave-uniform -> s_load
            float4 qv[2], kv[4];
            qv[0] = *(const float4*)&qs[qr][hh];
            qv[1] = *(const float4*)&qs[qr + 8][hh];
#pragma unroll
            for (int c = 0; c < 4; ++c) kv[c] = *(const float4*)&ks[tj + 8 * c][hh];
#pragma unroll
            for (int i = 0; i < 2; ++i)
#pragma unroll
                for (int c = 0; c < 4; ++c) {
                    float e0 = ex2_(qv[i].x + kv[c].x);
                    float e1 = ex2_(qv[i].y + kv[c].y);
                    float e2 = ex2_(qv[i].z + kv[c].z);
                    float e3 = ex2_(qv[i].w + kv[c].w);
                    float aa = e0 + 1.0f, bb = e1 + 1.0f;
                    float cc = e2 + 1.0f, dd = e3 + 1.0f;
                    float ab = aa * bb, cd = cc * dd;
                    float n1 = __builtin_fmaf(w4.y, aa, w4.x * bb);
                    float n2 = __builtin_fmaf(w4.w, cc, w4.z * dd);
                    float num = __builtin_fmaf(n2, ab, n1 * cd);
                    acc[i][c] = __builtin_fmaf(num, rcp_(ab * cd), acc[i][c]);
                }
        }
    }
#pragma unroll
    for (int i = 0; i < 2; ++i)
#pragma unroll
        for (int c = 0; c < 4; ++c)
            sc[((size_t)(b * QN) + i0 + qr + 8 * i) * KVN + j0 + tj + 8 * c] =
                -2.0f * acc[i][c];
}

// ---------------- K3: in-place softmax over last dim (512) ----------------
__global__ __launch_bounds__(256) void softmax_kernel(float* __restrict__ attn) {
    int row = blockIdx.x;
    int tid = threadIdx.x;
    float* p = attn + (size_t)row * KVN;
    float x0 = p[tid], x1 = p[tid + 256];
    float m = fmaxf(x0, x1);
#pragma unroll
    for (int d = 1; d < 64; d <<= 1) m = fmaxf(m, __shfl_xor(m, d));
    __shared__ float redm[4], reds[4];
    int wave = tid >> 6, lane = tid & 63;
    if (lane == 0) redm[wave] = m;
    __syncthreads();
    m = fmaxf(fmaxf(redm[0], redm[1]), fmaxf(redm[2], redm[3]));
    float e0 = __expf(x0 - m), e1 = __expf(x1 - m);
    float s = e0 + e1;
#pragma unroll
    for (int d = 1; d < 64; d <<= 1) s += __shfl_xor(s, d);
    if (lane == 0) reds[wave] = s;
    __syncthreads();
    s = reds[0] + reds[1] + reds[2] + reds[3];
    float inv = rcp_(s);
    p[tid] = e0 * inv;
    p[tid + 256] = e1 * inv;
}

// ---------------- K4: out[b][i][n] = sum_j attn[b][i][j]*v[b][j][n] ---------------------
// Same skeleton as K1: attn staged in LDS k-major; v rows (contiguous 8 cols) via
// wave-uniform s_load.
__global__ __launch_bounds__(256) void out_gemm(const float* __restrict__ attn,
                                                const float* __restrict__ v,
                                                float* __restrict__ out) {
    const int b = blockIdx.z;
    __shared__ float As[8 * 66 * 4];
    const int tid = threadIdx.x, lane = tid & 63;
    const int wid = __builtin_amdgcn_readfirstlane(tid >> 6);
    const int r0 = blockIdx.y * 64;
    const int n0 = blockIdx.x * 32 + wid * 8;
    const float* __restrict__ ap = attn + (size_t)b * QN * KVN;
    const float* __restrict__ vp = v + (size_t)b * KVN * VD_ + n0;
    float acc[8] = {};
    for (int k0 = 0; k0 < KVN; k0 += 32) {
        __syncthreads();
#pragma unroll
        for (int rep = 0; rep < 2; ++rep) {
            int idx = tid + rep * 256;
            int row = idx >> 3, c4 = idx & 7;
            float4 v4 = *(const float4*)(ap + (size_t)(r0 + row) * KVN + k0 + c4 * 4);
            *(float4*)(As + (c4 * 66 + row) * 4) = v4;
        }
        __syncthreads();
#pragma unroll
        for (int kq = 0; kq < 8; ++kq) {
            float4 a = *(const float4*)(As + (kq * 66 + lane) * 4);
            const float* vr = vp + (size_t)(k0 + kq * 4) * VD_;
#pragma unroll
            for (int j = 0; j < 4; ++j) {
                float aj = j == 0 ? a.x : j == 1 ? a.y : j == 2 ? a.z : a.w;
                float4 v0 = *(const float4*)(vr + (size_t)j * VD_);
                float4 v1 = *(const float4*)(vr + (size_t)j * VD_ + 4);
                acc[0] = __builtin_fmaf(aj, v0.x, acc[0]);
                acc[1] = __builtin_fmaf(aj, v0.y, acc[1]);
                acc[2] = __builtin_fmaf(aj, v0.z, acc[2]);
                acc[3] = __builtin_fmaf(aj, v0.w, acc[3]);
                acc[4] = __builtin_fmaf(aj, v1.x, acc[4]);
                acc[5] = __builtin_fmaf(aj, v1.y, acc[5]);
                acc[6] = __builtin_fmaf(aj, v1.z, acc[6]);
                acc[7] = __builtin_fmaf(aj, v1.w, acc[7]);
            }
        }
    }
    float* op = out + ((size_t)b * QN + r0 + lane) * VD_ + n0;
    float4 o0 = {acc[0], acc[1], acc[2], acc[3]};
    float4 o1 = {acc[4], acc[5], acc[6], acc[7]};
    *(float4*)op = o0;
    *(float4*)(op + 4) = o1;
}

extern "C" void kernel_launch(void* const* d_in, const int* in_sizes, int n_in,
                              void* d_out, int out_size, void* d_ws, size_t ws_size,
                              hipStream_t stream) {
    const float* q  = (const float*)d_in[0];
    const float* k  = (const float*)d_in[1];
    const float* v  = (const float*)d_in[2];
    const float* Wq = (const float*)d_in[3];
    const float* Wk = (const float*)d_in[4];
    const float* wv = (const float*)d_in[5];
    float* out  = (float*)d_out;                   // [B, QN, VD]
    float* attn = out + (size_t)B_ * QN * VD_;     // [B, QN, KVN]
    float* qh = (float*)d_ws;                      // [B*QN, H] (prescaled by 2*log2e)
    float* kh = qh + (size_t)B_ * QN * H_;         // [B*KVN, H] (prescaled)

    proj_fused<<<dim3(H_ / 32, (B_ * QN) / 64, 2), 256, 0, stream>>>(q, k, Wq, Wk, qh, kh);
    scores_kernel<<<dim3(KVN / 32, QN / 32, B_), 128, 0, stream>>>(qh, kh, wv, attn);
    softmax_kernel<<<B_ * QN, 256, 0, stream>>>(attn);
    out_gemm<<<dim3(VD_ / 32, QN / 64, B_), 256, 0, stream>>>(attn, v, out);
}

// Round 5
// 113.549 us; speedup vs baseline: 1.7979x; 1.4083x over previous
//
#include <hip/hip_runtime.h>

#define B_ 4
#define QN 512
#define KVN 512
#define QD_ 512
#define H_ 256
#define VD_ 256

typedef __attribute__((ext_vector_type(8))) short bf16x8;
typedef __attribute__((ext_vector_type(4))) float f32x4;
typedef __attribute__((ext_vector_type(4))) unsigned short u16x4;
typedef unsigned short u16;

__device__ __forceinline__ float rcp_(float x) { return __builtin_amdgcn_rcpf(x); }
__device__ __forceinline__ float ex2_(float x) { return __builtin_amdgcn_exp2f(x); }

__device__ __forceinline__ u16 bf16_rne(float x) {
    unsigned u = __float_as_uint(x);
    unsigned r = u + 0x7FFFu + ((u >> 16) & 1u);
    return (u16)(r >> 16);
}
__device__ __forceinline__ void split2(float x, u16& h, u16& l) {
    h = bf16_rne(x);
    float hf = __uint_as_float((unsigned)h << 16);
    l = bf16_rne(x - hf);
}
__device__ __forceinline__ void split4(float4 a, u16x4& h, u16x4& l) {
    u16 hh, ll;
    split2(a.x, hh, ll); h[0] = hh; l[0] = ll;
    split2(a.y, hh, ll); h[1] = hh; l[1] = ll;
    split2(a.z, hh, ll); h[2] = hh; l[2] = ll;
    split2(a.w, hh, ll); h[3] = hh; l[3] = ll;
}

// ---------------- K1: proj via split-bf16 MFMA --------------------------------------
// C[r][h] = (sum_d A[r][d]*W[h][d]) * 2log2e.  1 wave, tile 32x32, BK=32.
// LDS planes [kg][row][8]: frag = 8 contiguous k at k=8*kg; A-frag row=lane&15,
// kg=lane>>4 (AMD 16x16x32 layout); D: col=lane&15, row=4*(lane>>4)+reg (m89).
__global__ __launch_bounds__(64) void proj_mfma(const float* __restrict__ q,
                                                const float* __restrict__ k,
                                                const float* __restrict__ Wq,
                                                const float* __restrict__ Wk,
                                                float* __restrict__ qh,
                                                float* __restrict__ kh) {
    const int z = blockIdx.z;
    const float* __restrict__ A = z ? k : q;
    const float* __restrict__ W = z ? Wk : Wq;
    float* __restrict__ C = z ? kh : qh;
    __shared__ __attribute__((aligned(16))) u16 Ah[4][32][8], Al[4][32][8];
    __shared__ __attribute__((aligned(16))) u16 Bh[4][32][8], Bl[4][32][8];
    const int tid = threadIdx.x;
    const int r0 = blockIdx.y * 32;
    const int n0 = blockIdx.x * 32;
    f32x4 acc[2][2] = {};
    const int fl = tid & 15, kg = tid >> 4;
    for (int k0 = 0; k0 < QD_; k0 += 32) {
        __syncthreads();
#pragma unroll
        for (int t = 0; t < 4; ++t) {  // A tile 32 rows x 32 k
            int idx = t * 64 + tid;
            int m = idx >> 3, kq = idx & 7;  // 8 lanes cover 128B of one row
            float4 a4 = *(const float4*)(A + (size_t)(r0 + m) * QD_ + k0 + kq * 4);
            u16x4 h, l;
            split4(a4, h, l);
            *(u16x4*)&Ah[kq >> 1][m][(kq & 1) * 4] = h;
            *(u16x4*)&Al[kq >> 1][m][(kq & 1) * 4] = l;
        }
#pragma unroll
        for (int t = 0; t < 4; ++t) {  // W tile 32 rows x 32 k
            int idx = t * 64 + tid;
            int n = idx >> 3, kq = idx & 7;
            float4 b4 = *(const float4*)(W + (size_t)(n0 + n) * QD_ + k0 + kq * 4);
            u16x4 h, l;
            split4(b4, h, l);
            *(u16x4*)&Bh[kq >> 1][n][(kq & 1) * 4] = h;
            *(u16x4*)&Bl[kq >> 1][n][(kq & 1) * 4] = l;
        }
        __syncthreads();
        bf16x8 ah[2], al[2], bh[2], bl[2];
#pragma unroll
        for (int t = 0; t < 2; ++t) {
            ah[t] = *(const bf16x8*)Ah[kg][fl + 16 * t];
            al[t] = *(const bf16x8*)Al[kg][fl + 16 * t];
            bh[t] = *(const bf16x8*)Bh[kg][fl + 16 * t];
            bl[t] = *(const bf16x8*)Bl[kg][fl + 16 * t];
        }
#pragma unroll
        for (int mt = 0; mt < 2; ++mt)
#pragma unroll
            for (int nt = 0; nt < 2; ++nt) {
                acc[mt][nt] = __builtin_amdgcn_mfma_f32_16x16x32_bf16(ah[mt], bh[nt], acc[mt][nt], 0, 0, 0);
                acc[mt][nt] = __builtin_amdgcn_mfma_f32_16x16x32_bf16(ah[mt], bl[nt], acc[mt][nt], 0, 0, 0);
                acc[mt][nt] = __builtin_amdgcn_mfma_f32_16x16x32_bf16(al[mt], bh[nt], acc[mt][nt], 0, 0, 0);
            }
    }
    const float cs = 2.8853900817779268f;  // 2*log2(e): prescale for scores' exp2
    const int rg = (tid >> 4) * 4;
#pragma unroll
    for (int mt = 0; mt < 2; ++mt)
#pragma unroll
        for (int nt = 0; nt < 2; ++nt)
#pragma unroll
            for (int r = 0; r < 4; ++r)
                C[(size_t)(r0 + mt * 16 + rg + r) * H_ + n0 + nt * 16 + fl] =
                    acc[mt][nt][r] * cs;
}

// ---------------- vtrans: v[b][j][n] -> vt_hi/lo[b][n][j] bf16 planes -------------------
__global__ __launch_bounds__(256) void vtrans(const float* __restrict__ v,
                                              u16* __restrict__ vt_hi,
                                              u16* __restrict__ vt_lo) {
    __shared__ float ts[64][65];
    const int b = blockIdx.z;
    const int j0 = blockIdx.x * 64, n0 = blockIdx.y * 64;
    const int tid = threadIdx.x;
#pragma unroll
    for (int t = 0; t < 4; ++t) {
        int idx = t * 256 + tid;
        int j = idx >> 4, nq = idx & 15;
        float4 v4 = *(const float4*)(v + ((size_t)b * KVN + j0 + j) * VD_ + n0 + nq * 4);
        *(float4*)&ts[j][nq * 4] = v4;
    }
    __syncthreads();
#pragma unroll
    for (int t = 0; t < 4; ++t) {
        int idx = t * 256 + tid;
        int jq = idx & 15, n = idx >> 4;  // lanes along j -> coalesced u16x4 stores
        u16x4 h, l;
        u16 hh, ll;
#pragma unroll
        for (int e = 0; e < 4; ++e) {
            split2(ts[jq * 4 + e][n], hh, ll);
            h[e] = hh; l[e] = ll;
        }
        size_t off = ((size_t)b * VD_ + n0 + n) * KVN + j0 + jq * 4;
        *(u16x4*)(vt_hi + off) = h;
        *(u16x4*)(vt_lo + off) = l;
    }
}

// ---------------- K2: sc = -2 * sum_h wv[h] * rcp(exp2(qh'+kh')+1) ----------------------
__global__ __launch_bounds__(128) void scores_kernel(const float* __restrict__ qh,
                                                     const float* __restrict__ kh,
                                                     const float* __restrict__ wv,
                                                     float* __restrict__ sc) {
    __shared__ float qs[32][68];
    __shared__ float ks[32][68];
    const int b = blockIdx.z;
    const int i0 = blockIdx.y * 32, j0 = blockIdx.x * 32;
    const int tid = threadIdx.x;
    const int w = tid >> 6, lane = tid & 63;
    const int ti = lane >> 3, tj = lane & 7;
    const int qr = 16 * w + ti;
    float acc[2][4] = {};
    for (int h0 = 0; h0 < H_; h0 += 64) {
        __syncthreads();
#pragma unroll
        for (int t = 0; t < 8; ++t) {
            int idx = tid + t * 128;
            int row = (idx >> 4) & 31, c = idx & 15;
            if (t < 4) {
                float4 v4 = *(const float4*)(qh + ((size_t)(b * QN + i0 + row)) * H_ + h0 + c * 4);
                *(float4*)&qs[row][c * 4] = v4;
            } else {
                float4 v4 = *(const float4*)(kh + ((size_t)(b * KVN + j0 + row)) * H_ + h0 + c * 4);
                *(float4*)&ks[row][c * 4] = v4;
            }
        }
        __syncthreads();
#pragma unroll 4
        for (int hh = 0; hh < 64; hh += 4) {
            float4 w4 = *(const float4*)(wv + h0 + hh);
            float4 qv[2], kv[4];
            qv[0] = *(const float4*)&qs[qr][hh];
            qv[1] = *(const float4*)&qs[qr + 8][hh];
#pragma unroll
            for (int c = 0; c < 4; ++c) kv[c] = *(const float4*)&ks[tj + 8 * c][hh];
#pragma unroll
            for (int i = 0; i < 2; ++i)
#pragma unroll
                for (int c = 0; c < 4; ++c) {
                    float e0 = ex2_(qv[i].x + kv[c].x);
                    float e1 = ex2_(qv[i].y + kv[c].y);
                    float e2 = ex2_(qv[i].z + kv[c].z);
                    float e3 = ex2_(qv[i].w + kv[c].w);
                    float aa = e0 + 1.0f, bb = e1 + 1.0f;
                    float cc = e2 + 1.0f, dd = e3 + 1.0f;
                    float ab = aa * bb, cd = cc * dd;
                    float n1 = __builtin_fmaf(w4.y, aa, w4.x * bb);
                    float n2 = __builtin_fmaf(w4.w, cc, w4.z * dd);
                    float num = __builtin_fmaf(n2, ab, n1 * cd);
                    acc[i][c] = __builtin_fmaf(num, rcp_(ab * cd), acc[i][c]);
                }
        }
    }
#pragma unroll
    for (int i = 0; i < 2; ++i)
#pragma unroll
        for (int c = 0; c < 4; ++c)
            sc[((size_t)(b * QN) + i0 + qr + 8 * i) * KVN + j0 + tj + 8 * c] =
                -2.0f * acc[i][c];
}

// ---------------- K3: in-place softmax over last dim (512) ----------------
__global__ __launch_bounds__(256) void softmax_kernel(float* __restrict__ attn) {
    int row = blockIdx.x;
    int tid = threadIdx.x;
    float* p = attn + (size_t)row * KVN;
    float x0 = p[tid], x1 = p[tid + 256];
    float m = fmaxf(x0, x1);
#pragma unroll
    for (int d = 1; d < 64; d <<= 1) m = fmaxf(m, __shfl_xor(m, d));
    __shared__ float redm[4], reds[4];
    int wave = tid >> 6, lane = tid & 63;
    if (lane == 0) redm[wave] = m;
    __syncthreads();
    m = fmaxf(fmaxf(redm[0], redm[1]), fmaxf(redm[2], redm[3]));
    float e0 = __expf(x0 - m), e1 = __expf(x1 - m);
    float s = e0 + e1;
#pragma unroll
    for (int d = 1; d < 64; d <<= 1) s += __shfl_xor(s, d);
    if (lane == 0) reds[wave] = s;
    __syncthreads();
    s = reds[0] + reds[1] + reds[2] + reds[3];
    float inv = rcp_(s);
    p[tid] = e0 * inv;
    p[tid + 256] = e1 * inv;
}

// ---------------- K4: out via split-bf16 MFMA (swapped operands) ------------------------
// D[n][i] = sum_j vt[n][j] * attn[i][j]; both frags read j-contiguous; D-regs are 4
// consecutive n for fixed i -> coalesced float4 stores of out[i][n0..n0+3].
__global__ __launch_bounds__(64) void out_mfma(const u16* __restrict__ vt_hi,
                                               const u16* __restrict__ vt_lo,
                                               const float* __restrict__ attn,
                                               float* __restrict__ out) {
    __shared__ __attribute__((aligned(16))) u16 Ah[4][32][8], Al[4][32][8];
    __shared__ __attribute__((aligned(16))) u16 Bh[4][32][8], Bl[4][32][8];
    const int b = blockIdx.z;
    const int i0 = blockIdx.x * 32;
    const int n0 = blockIdx.y * 32;
    const int tid = threadIdx.x;
    const int fl = tid & 15, kg = tid >> 4;
    f32x4 acc[2][2] = {};
    for (int k0 = 0; k0 < KVN; k0 += 32) {
        __syncthreads();
#pragma unroll
        for (int t = 0; t < 2; ++t) {  // vt tiles: 32 n-rows x 4 kg-groups, u16x8 copies
            int idx = t * 64 + tid;
            int n = idx >> 2, kq = idx & 3;
            size_t off = ((size_t)b * VD_ + n0 + n) * KVN + k0 + kq * 8;
            *(uint4*)&Ah[kq][n][0] = *(const uint4*)(vt_hi + off);
            *(uint4*)&Al[kq][n][0] = *(const uint4*)(vt_lo + off);
        }
#pragma unroll
        for (int t = 0; t < 4; ++t) {  // attn tile 32 i-rows x 32 j, fp32 -> split
            int idx = t * 64 + tid;
            int m = idx >> 3, kq = idx & 7;
            float4 a4 = *(const float4*)(attn + ((size_t)b * QN + i0 + m) * KVN + k0 + kq * 4);
            u16x4 h, l;
            split4(a4, h, l);
            *(u16x4*)&Bh[kq >> 1][m][(kq & 1) * 4] = h;
            *(u16x4*)&Bl[kq >> 1][m][(kq & 1) * 4] = l;
        }
        __syncthreads();
        bf16x8 ah[2], al[2], bh[2], bl[2];
#pragma unroll
        for (int t = 0; t < 2; ++t) {
            ah[t] = *(const bf16x8*)Ah[kg][fl + 16 * t];
            al[t] = *(const bf16x8*)Al[kg][fl + 16 * t];
            bh[t] = *(const bf16x8*)Bh[kg][fl + 16 * t];
            bl[t] = *(const bf16x8*)Bl[kg][fl + 16 * t];
        }
#pragma unroll
        for (int mt = 0; mt < 2; ++mt)
#pragma unroll
            for (int nt = 0; nt < 2; ++nt) {
                acc[mt][nt] = __builtin_amdgcn_mfma_f32_16x16x32_bf16(ah[mt], bh[nt], acc[mt][nt], 0, 0, 0);
                acc[mt][nt] = __builtin_amdgcn_mfma_f32_16x16x32_bf16(ah[mt], bl[nt], acc[mt][nt], 0, 0, 0);
                acc[mt][nt] = __builtin_amdgcn_mfma_f32_16x16x32_bf16(al[mt], bh[nt], acc[mt][nt], 0, 0, 0);
            }
    }
    const int rg = (tid >> 4) * 4;
#pragma unroll
    for (int mt = 0; mt < 2; ++mt)
#pragma unroll
        for (int nt = 0; nt < 2; ++nt) {
            float4 o;
            o.x = acc[mt][nt][0];
            o.y = acc[mt][nt][1];
            o.z = acc[mt][nt][2];
            o.w = acc[mt][nt][3];
            *(float4*)(out + ((size_t)b * QN + i0 + nt * 16 + fl) * VD_ + n0 + mt * 16 + rg) = o;
        }
}

extern "C" void kernel_launch(void* const* d_in, const int* in_sizes, int n_in,
                              void* d_out, int out_size, void* d_ws, size_t ws_size,
                              hipStream_t stream) {
    const float* q  = (const float*)d_in[0];
    const float* k  = (const float*)d_in[1];
    const float* v  = (const float*)d_in[2];
    const float* Wq = (const float*)d_in[3];
    const float* Wk = (const float*)d_in[4];
    const float* wv = (const float*)d_in[5];
    float* out  = (float*)d_out;                   // [B, QN, VD]
    float* attn = out + (size_t)B_ * QN * VD_;     // [B, QN, KVN]
    float* qh = (float*)d_ws;                      // [B*QN, H]  (prescaled by 2*log2e)
    float* kh = qh + (size_t)B_ * QN * H_;         // [B*KVN, H] (prescaled)
    u16* vt_hi = (u16*)(kh + (size_t)B_ * KVN * H_);             // [B][VD][KVN]
    u16* vt_lo = vt_hi + (size_t)B_ * VD_ * KVN;                 // [B][VD][KVN]

    vtrans<<<dim3(KVN / 64, VD_ / 64, B_), 256, 0, stream>>>(v, vt_hi, vt_lo);
    proj_mfma<<<dim3(H_ / 32, (B_ * QN) / 32, 2), 64, 0, stream>>>(q, k, Wq, Wk, qh, kh);
    scores_kernel<<<dim3(KVN / 32, QN / 32, B_), 128, 0, stream>>>(qh, kh, wv, attn);
    softmax_kernel<<<B_ * QN, 256, 0, stream>>>(attn);
    out_mfma<<<dim3(QN / 32, VD_ / 32, B_), 64, 0, stream>>>(vt_hi, vt_lo, attn, out);
}

// Round 6
// 73.831 us; speedup vs baseline: 2.7650x; 1.5380x over previous
//
#include <hip/hip_runtime.h>

#define B_ 4
#define QN 512
#define KVN 512
#define QD_ 512
#define H_ 256
#define VD_ 256

typedef __attribute__((ext_vector_type(8))) short bf16x8;
typedef __attribute__((ext_vector_type(4))) float f32x4;
typedef __attribute__((ext_vector_type(4))) unsigned short u16x4;
typedef unsigned short u16;

__device__ __forceinline__ float rcp_(float x) { return __builtin_amdgcn_rcpf(x); }
__device__ __forceinline__ float ex2_(float x) { return __builtin_amdgcn_exp2f(x); }

__device__ __forceinline__ u16 bf16_rne(float x) {
    unsigned u = __float_as_uint(x);
    unsigned r = u + 0x7FFFu + ((u >> 16) & 1u);
    return (u16)(r >> 16);
}
__device__ __forceinline__ void split2(float x, u16& h, u16& l) {
    h = bf16_rne(x);
    float hf = __uint_as_float((unsigned)h << 16);
    l = bf16_rne(x - hf);
}
__device__ __forceinline__ void split4(float4 a, u16x4& h, u16x4& l) {
    u16 hh, ll;
    split2(a.x, hh, ll); h[0] = hh; l[0] = ll;
    split2(a.y, hh, ll); h[1] = hh; l[1] = ll;
    split2(a.z, hh, ll); h[2] = hh; l[2] = ll;
    split2(a.w, hh, ll); h[3] = hh; l[3] = ll;
}

// ---------------- presplit: q,k,Wq,Wk fp32 -> bf16 hi/lo planes (memory-bound) ----------
__global__ __launch_bounds__(256) void presplit(const float* __restrict__ q,
                                                const float* __restrict__ k,
                                                const float* __restrict__ Wq,
                                                const float* __restrict__ Wk,
                                                u16* __restrict__ q_hi, u16* __restrict__ q_lo,
                                                u16* __restrict__ k_hi, u16* __restrict__ k_lo,
                                                u16* __restrict__ w_hi, u16* __restrict__ w_lo) {
    const int NQ = 2048 * 512 / 4, NW = 256 * 512 / 4;  // float4 counts
    int idx = blockIdx.x * 256 + threadIdx.x;           // grid sized exactly
    const float* src; u16 *dh, *dl; int off;
    if (idx < NQ)             { src = q;  dh = q_hi; dl = q_lo; off = idx; }
    else if (idx < 2 * NQ)    { src = k;  dh = k_hi; dl = k_lo; off = idx - 2 * NQ + NQ; }
    else if (idx < 2 * NQ + NW) { src = Wq; dh = w_hi; dl = w_lo; off = idx - 2 * NQ; }
    else { src = Wk; dh = w_hi + 256 * 512; dl = w_lo + 256 * 512; off = idx - 2 * NQ - NW; }
    float4 v4 = ((const float4*)src)[off];
    u16x4 h, l;
    split4(v4, h, l);
    *(u16x4*)(dh + off * 4) = h;
    *(u16x4*)(dl + off * 4) = l;
}

// ---------------- vtrans: v[b][j][n] -> vt_hi/lo[b][n][j] bf16 planes -------------------
__global__ __launch_bounds__(256) void vtrans(const float* __restrict__ v,
                                              u16* __restrict__ vt_hi,
                                              u16* __restrict__ vt_lo) {
    __shared__ float ts[64][65];
    const int b = blockIdx.z;
    const int j0 = blockIdx.x * 64, n0 = blockIdx.y * 64;
    const int tid = threadIdx.x;
#pragma unroll
    for (int t = 0; t < 4; ++t) {
        int idx = t * 256 + tid;
        int j = idx >> 4, nq = idx & 15;
        float4 v4 = *(const float4*)(v + ((size_t)b * KVN + j0 + j) * VD_ + n0 + nq * 4);
        *(float4*)&ts[j][nq * 4] = v4;
    }
    __syncthreads();
#pragma unroll
    for (int t = 0; t < 4; ++t) {
        int idx = t * 256 + tid;
        int jq = idx & 15, n = idx >> 4;
        u16x4 h, l;
        u16 hh, ll;
#pragma unroll
        for (int e = 0; e < 4; ++e) {
            split2(ts[jq * 4 + e][n], hh, ll);
            h[e] = hh; l[e] = ll;
        }
        size_t off = ((size_t)b * VD_ + n0 + n) * KVN + j0 + jq * 4;
        *(u16x4*)(vt_hi + off) = h;
        *(u16x4*)(vt_lo + off) = l;
    }
}

// ---------------- proj: eq/ek[r][h] = exp2( (sum_d A[r][d]*W[h][d]) * 2log2e ) ----------
// 32x32 tile, 4 waves as 2x2 of 16x16; presplit bf16 planes; 3-MFMA fp32 emulation.
__global__ __launch_bounds__(256) void proj_mfma(const u16* __restrict__ q_hi, const u16* __restrict__ q_lo,
                                                 const u16* __restrict__ k_hi, const u16* __restrict__ k_lo,
                                                 const u16* __restrict__ w_hi, const u16* __restrict__ w_lo,
                                                 float* __restrict__ eq, float* __restrict__ ek) {
    const int z = blockIdx.z;
    const u16* __restrict__ Ah_g = z ? k_hi : q_hi;
    const u16* __restrict__ Al_g = z ? k_lo : q_lo;
    const u16* __restrict__ Bh_g = w_hi + (size_t)z * H_ * QD_;
    const u16* __restrict__ Bl_g = w_lo + (size_t)z * H_ * QD_;
    float* __restrict__ C = z ? ek : eq;
    __shared__ u16 Ash[4][32][8], Asl[4][32][8], Bsh[4][32][8], Bsl[4][32][8];
    const int tid = threadIdx.x;
    const int wave = tid >> 6, lane = tid & 63;
    const int fl = lane & 15, kg = lane >> 4;
    const int r0 = blockIdx.y * 32, c0 = blockIdx.x * 32;
    const int ar = 16 * (wave & 1), bc = 16 * (wave >> 1);
    const int frow = (tid & 127) >> 2, fkq = tid & 3, fsel = tid >> 7;
    f32x4 acc = {};
    for (int k0 = 0; k0 < QD_; k0 += 32) {
        __syncthreads();
        {
            const u16* as = (fsel ? Al_g : Ah_g) + (size_t)(r0 + frow) * QD_ + k0 + fkq * 8;
            u16* ad = fsel ? &Asl[fkq][frow][0] : &Ash[fkq][frow][0];
            *(uint4*)ad = *(const uint4*)as;
            const u16* bs = (fsel ? Bl_g : Bh_g) + (size_t)(c0 + frow) * QD_ + k0 + fkq * 8;
            u16* bd = fsel ? &Bsl[fkq][frow][0] : &Bsh[fkq][frow][0];
            *(uint4*)bd = *(const uint4*)bs;
        }
        __syncthreads();
        bf16x8 a_h = *(const bf16x8*)&Ash[kg][ar + fl][0];
        bf16x8 a_l = *(const bf16x8*)&Asl[kg][ar + fl][0];
        bf16x8 b_h = *(const bf16x8*)&Bsh[kg][bc + fl][0];
        bf16x8 b_l = *(const bf16x8*)&Bsl[kg][bc + fl][0];
        acc = __builtin_amdgcn_mfma_f32_16x16x32_bf16(a_h, b_h, acc, 0, 0, 0);
        acc = __builtin_amdgcn_mfma_f32_16x16x32_bf16(a_h, b_l, acc, 0, 0, 0);
        acc = __builtin_amdgcn_mfma_f32_16x16x32_bf16(a_l, b_h, acc, 0, 0, 0);
    }
    const float cs = 2.8853900817779268f;  // 2*log2(e)
    const int rg = kg * 4;
#pragma unroll
    for (int r = 0; r < 4; ++r)
        C[(size_t)(r0 + ar + rg + r) * H_ + c0 + bc + fl] = ex2_(acc[r] * cs);
}

// ---------------- scores: sc = -2 * sum_h wv[h] * rcp(1 + eq*ek) ------------------------
// (scores minus row-const sum(wv); softmax shift-invariant). 4-way rcp combine over h;
// a = fma(eq,ek,1): 14 VALU + 0.25 rcp per eval-group-of-4. 1q x 2k per thread.
__device__ __forceinline__ float grp4(float4 qv, float4 kv, float4 w4, float acc) {
    float a = __builtin_fmaf(qv.x, kv.x, 1.0f);
    float b = __builtin_fmaf(qv.y, kv.y, 1.0f);
    float c = __builtin_fmaf(qv.z, kv.z, 1.0f);
    float d = __builtin_fmaf(qv.w, kv.w, 1.0f);
    float ab = a * b, cd = c * d;
    float n1 = __builtin_fmaf(w4.y, a, w4.x * b);
    float n2 = __builtin_fmaf(w4.w, c, w4.z * d);
    float num = __builtin_fmaf(n2, ab, n1 * cd);
    return __builtin_fmaf(num, rcp_(ab * cd), acc);
}

__global__ __launch_bounds__(256, 4) void scores_kernel(const float* __restrict__ eq,
                                                        const float* __restrict__ ek,
                                                        const float* __restrict__ wv,
                                                        float* __restrict__ sc) {
    __shared__ float qs[16][68];
    __shared__ float ks[32][68];
    const int b = blockIdx.z;
    const int i0 = blockIdx.y * 16, j0 = blockIdx.x * 32;
    const int tid = threadIdx.x;
    const int wid = tid >> 6, lane = tid & 63;
    const int qr = (wid << 2) + (lane >> 4), kc = lane & 15;
    float acc0 = 0.f, acc1 = 0.f;
    for (int h0 = 0; h0 < H_; h0 += 64) {
        __syncthreads();
        {
            int r1 = tid >> 4, c1 = tid & 15;
            *(float4*)&qs[r1][c1 * 4] =
                *(const float4*)(eq + (size_t)(b * QN + i0 + r1) * H_ + h0 + c1 * 4);
#pragma unroll
            for (int t = 0; t < 2; ++t) {
                int idx = t * 256 + tid;
                int r2 = idx >> 4, c2 = idx & 15;
                *(float4*)&ks[r2][c2 * 4] =
                    *(const float4*)(ek + (size_t)(b * KVN + j0 + r2) * H_ + h0 + c2 * 4);
            }
        }
        __syncthreads();
#pragma unroll 4
        for (int hh = 0; hh < 64; hh += 4) {
            float4 w4 = *(const float4*)(wv + h0 + hh);  // uniform -> s_load
            float4 qv = *(const float4*)&qs[qr][hh];
            float4 k0v = *(const float4*)&ks[kc][hh];
            float4 k1v = *(const float4*)&ks[kc + 16][hh];
            acc0 = grp4(qv, k0v, w4, acc0);
            acc1 = grp4(qv, k1v, w4, acc1);
        }
    }
    sc[(size_t)(b * QN + i0 + qr) * KVN + j0 + kc] = -2.0f * acc0;
    sc[(size_t)(b * QN + i0 + qr) * KVN + j0 + kc + 16] = -2.0f * acc1;
}

// ---------------- softmax (in-place fp32) + bf16 hi/lo plane emit -----------------------
__global__ __launch_bounds__(256) void softmax_kernel(float* __restrict__ attn,
                                                      u16* __restrict__ at_hi,
                                                      u16* __restrict__ at_lo) {
    int row = blockIdx.x;
    int tid = threadIdx.x;
    float* p = attn + (size_t)row * KVN;
    float x0 = p[tid], x1 = p[tid + 256];
    float m = fmaxf(x0, x1);
#pragma unroll
    for (int d = 1; d < 64; d <<= 1) m = fmaxf(m, __shfl_xor(m, d));
    __shared__ float redm[4], reds[4];
    int wave = tid >> 6, lane = tid & 63;
    if (lane == 0) redm[wave] = m;
    __syncthreads();
    m = fmaxf(fmaxf(redm[0], redm[1]), fmaxf(redm[2], redm[3]));
    float e0 = __expf(x0 - m), e1 = __expf(x1 - m);
    float s = e0 + e1;
#pragma unroll
    for (int d = 1; d < 64; d <<= 1) s += __shfl_xor(s, d);
    if (lane == 0) reds[wave] = s;
    __syncthreads();
    s = reds[0] + reds[1] + reds[2] + reds[3];
    float inv = rcp_(s);
    float r0v = e0 * inv, r1v = e1 * inv;
    p[tid] = r0v;
    p[tid + 256] = r1v;
    u16 h, l;
    size_t base = (size_t)row * KVN;
    split2(r0v, h, l);
    at_hi[base + tid] = h; at_lo[base + tid] = l;
    split2(r1v, h, l);
    at_hi[base + tid + 256] = h; at_lo[base + tid + 256] = l;
}

// ---------------- out: out[b][i][n] = sum_j attn[b][i][j] * v[b][j][n] ------------------
// D[n][i] via A=vt (n-rows, j-contig), B=at (i-rows, j-contig); float4 stores along n.
__global__ __launch_bounds__(256) void out_mfma(const u16* __restrict__ vt_hi, const u16* __restrict__ vt_lo,
                                                const u16* __restrict__ at_hi, const u16* __restrict__ at_lo,
                                                float* __restrict__ out) {
    const int b = blockIdx.z;
    const u16* __restrict__ Ah_g = vt_hi + (size_t)b * VD_ * KVN;
    const u16* __restrict__ Al_g = vt_lo + (size_t)b * VD_ * KVN;
    const u16* __restrict__ Bh_g = at_hi + (size_t)b * QN * KVN;
    const u16* __restrict__ Bl_g = at_lo + (size_t)b * QN * KVN;
    float* __restrict__ outb = out + (size_t)b * QN * VD_;
    __shared__ u16 Ash[4][32][8], Asl[4][32][8], Bsh[4][32][8], Bsl[4][32][8];
    const int tid = threadIdx.x;
    const int wave = tid >> 6, lane = tid & 63;
    const int fl = lane & 15, kg = lane >> 4;
    const int r0 = blockIdx.y * 32;  // n-tile
    const int c0 = blockIdx.x * 32;  // i-tile
    const int ar = 16 * (wave & 1), bc = 16 * (wave >> 1);
    const int frow = (tid & 127) >> 2, fkq = tid & 3, fsel = tid >> 7;
    f32x4 acc = {};
    for (int k0 = 0; k0 < KVN; k0 += 32) {
        __syncthreads();
        {
            const u16* as = (fsel ? Al_g : Ah_g) + (size_t)(r0 + frow) * KVN + k0 + fkq * 8;
            u16* ad = fsel ? &Asl[fkq][frow][0] : &Ash[fkq][frow][0];
            *(uint4*)ad = *(const uint4*)as;
            const u16* bs = (fsel ? Bl_g : Bh_g) + (size_t)(c0 + frow) * KVN + k0 + fkq * 8;
            u16* bd = fsel ? &Bsl[fkq][frow][0] : &Bsh[fkq][frow][0];
            *(uint4*)bd = *(const uint4*)bs;
        }
        __syncthreads();
        bf16x8 a_h = *(const bf16x8*)&Ash[kg][ar + fl][0];
        bf16x8 a_l = *(const bf16x8*)&Asl[kg][ar + fl][0];
        bf16x8 b_h = *(const bf16x8*)&Bsh[kg][bc + fl][0];
        bf16x8 b_l = *(const bf16x8*)&Bsl[kg][bc + fl][0];
        acc = __builtin_amdgcn_mfma_f32_16x16x32_bf16(a_h, b_h, acc, 0, 0, 0);
        acc = __builtin_amdgcn_mfma_f32_16x16x32_bf16(a_h, b_l, acc, 0, 0, 0);
        acc = __builtin_amdgcn_mfma_f32_16x16x32_bf16(a_l, b_h, acc, 0, 0, 0);
    }
    const int rg = kg * 4;
    float4 o = {acc[0], acc[1], acc[2], acc[3]};
    *(float4*)(outb + (size_t)(c0 + bc + fl) * VD_ + r0 + ar + rg) = o;
}

extern "C" void kernel_launch(void* const* d_in, const int* in_sizes, int n_in,
                              void* d_out, int out_size, void* d_ws, size_t ws_size,
                              hipStream_t stream) {
    const float* q  = (const float*)d_in[0];
    const float* k  = (const float*)d_in[1];
    const float* v  = (const float*)d_in[2];
    const float* Wq = (const float*)d_in[3];
    const float* Wk = (const float*)d_in[4];
    const float* wv = (const float*)d_in[5];
    float* out  = (float*)d_out;                   // [B, QN, VD]
    float* attn = out + (size_t)B_ * QN * VD_;     // [B, QN, KVN]

    float* eq = (float*)d_ws;                      // [2048][256] f32 (= exp2(qh'))
    float* ek = eq + 2048 * 256;                   // [2048][256] f32
    u16* q_hi = (u16*)(ek + 2048 * 256);           // [2048][512] u16 each
    u16* q_lo = q_hi + 2048 * 512;
    u16* k_hi = q_lo + 2048 * 512;
    u16* k_lo = k_hi + 2048 * 512;
    u16* w_hi = k_lo + 2048 * 512;                 // [512][512] (Wq rows 0-255, Wk 256-511)
    u16* w_lo = w_hi + 512 * 512;
    u16* vt_hi = w_lo + 512 * 512;                 // [4][256][512]
    u16* vt_lo = vt_hi + (size_t)B_ * VD_ * KVN;
    u16* at_hi = q_hi;                             // alias: q planes dead after proj
    u16* at_lo = q_lo;

    presplit<<<2304, 256, 0, stream>>>(q, k, Wq, Wk, q_hi, q_lo, k_hi, k_lo, w_hi, w_lo);
    vtrans<<<dim3(KVN / 64, VD_ / 64, B_), 256, 0, stream>>>(v, vt_hi, vt_lo);
    proj_mfma<<<dim3(H_ / 32, 2048 / 32, 2), 256, 0, stream>>>(q_hi, q_lo, k_hi, k_lo,
                                                               w_hi, w_lo, eq, ek);
    scores_kernel<<<dim3(KVN / 32, QN / 16, B_), 256, 0, stream>>>(eq, ek, wv, attn);
    softmax_kernel<<<B_ * QN, 256, 0, stream>>>(attn, at_hi, at_lo);
    out_mfma<<<dim3(QN / 32, VD_ / 32, B_), 256, 0, stream>>>(vt_hi, vt_lo, at_hi, at_lo, out);
}